// Round 2
// baseline (556.031 us; speedup 1.0000x reference)
//
#include <hip/hip_runtime.h>
#include <hip/hip_bf16.h>

typedef __bf16 bf16;
typedef __bf16 bf16x8 __attribute__((ext_vector_type(8)));
typedef float f32x4 __attribute__((ext_vector_type(4)));

// problem sizes
#define NN 8192
#define DIN 128
#define DTH 256
#define DH 64

// workspace layout (bytes)
#define OFF_PACC 0                         // 8192*64 f32 partial aggregation
#define OFF_PDEN (8192*64*4)               // 8192 f32 partial denominators
#define OFF_BN   (OFF_PDEN + 8192*4)       // 256 f32 bn sums (sum, sumsq)
#define OFF_HX   (OFF_BN + 1024)           // 8192*256 bf16 Hx
#define OFF_X2T  (OFF_HX + 8192*256*2)     // 64*8192 bf16 X2 transposed
#define ZERO_BYTES OFF_HX

// ---------------------------------------------------------------------------
// BN statistics: per-feature sum and sum-of-squares via per-block partials.
__global__ __launch_bounds__(256) void k_bn_stats(const float* __restrict__ H,
                                                  float* __restrict__ bns) {
    __shared__ float s1[256], s2[256];
    int t = threadIdx.x;
    int f = t & 127, rh = t >> 7;
    int r0 = blockIdx.x * 32 + rh * 16;
    float a = 0.f, b = 0.f;
#pragma unroll
    for (int rr = 0; rr < 16; ++rr) {
        float x = H[(size_t)(r0 + rr) * DIN + f];
        a += x; b += x * x;
    }
    s1[t] = a; s2[t] = b;
    __syncthreads();
    if (t < 128) {
        atomicAdd(&bns[f], s1[t] + s1[t + 128]);
        atomicAdd(&bns[128 + f], s2[t] + s2[t + 128]);
    }
}

// ---------------------------------------------------------------------------
// BN apply + projections: Hx = Hn@Wt+bt (bf16), out1 = leaky(Hn@W1+b1) (fp32,
// written directly to left half of output), X2T[c][row] = Hn@W2+b2 (bf16).
__global__ __launch_bounds__(256) void k_project(
    const float* __restrict__ H, const float* __restrict__ bns,
    const float* __restrict__ gamma, const float* __restrict__ beta,
    const float* __restrict__ Wt, const float* __restrict__ bt,
    const float* __restrict__ W1, const float* __restrict__ b1,
    const float* __restrict__ W2, const float* __restrict__ b2,
    bf16* __restrict__ Hx, bf16* __restrict__ X2T, float* __restrict__ out)
{
    __shared__ float Hn[16 * 128];
    int t = threadIdx.x;
    int r0 = blockIdx.x * 16;
    {   // BN apply: each thread owns feature f = t&127, rows t>>7 + 2p
        int f = t & 127;
        float mean = bns[f] * (1.f / 8192.f);
        float var  = bns[128 + f] * (1.f / 8192.f) - mean * mean;
        float sc = rsqrtf(var + 1e-5f) * gamma[f];
        float sh = beta[f];
        int rb = t >> 7;
#pragma unroll
        for (int p = 0; p < 8; ++p) {
            int row = rb + p * 2;
            float x = H[(size_t)(r0 + row) * DIN + f];
            Hn[row * 128 + f] = (x - mean) * sc + sh;
        }
    }
    __syncthreads();
    {   // Hx = Hn @ Wt + bt : thread -> 4 rows x 4 cols
        int c0 = t & 63, rg = t >> 6;
        float acc[4][4];
#pragma unroll
        for (int i = 0; i < 4; ++i)
#pragma unroll
            for (int j = 0; j < 4; ++j) acc[i][j] = 0.f;
        for (int k = 0; k < 128; ++k) {
            float h[4];
#pragma unroll
            for (int rr = 0; rr < 4; ++rr) h[rr] = Hn[(rg * 4 + rr) * 128 + k];
#pragma unroll
            for (int cc = 0; cc < 4; ++cc) {
                float wv = Wt[k * DTH + c0 + 64 * cc];
#pragma unroll
                for (int rr = 0; rr < 4; ++rr) acc[rr][cc] += h[rr] * wv;
            }
        }
#pragma unroll
        for (int rr = 0; rr < 4; ++rr) {
            int row = r0 + rg * 4 + rr;
#pragma unroll
            for (int cc = 0; cc < 4; ++cc) {
                int c = c0 + 64 * cc;
                Hx[(size_t)row * DTH + c] = (bf16)(acc[rr][cc] + bt[c]);
            }
        }
    }
    {   // out1 (fp32 exact) and X2T (bf16)
        int c = t & 63, rg = t >> 6;
        float a1[4] = {0,0,0,0}, a2[4] = {0,0,0,0};
        for (int k = 0; k < 128; ++k) {
            float w1 = W1[k * DH + c], w2 = W2[k * DH + c];
#pragma unroll
            for (int rr = 0; rr < 4; ++rr) {
                float h = Hn[(rg * 4 + rr) * 128 + k];
                a1[rr] += h * w1; a2[rr] += h * w2;
            }
        }
#pragma unroll
        for (int rr = 0; rr < 4; ++rr) {
            int row = r0 + rg * 4 + rr;
            float v1 = a1[rr] + b1[c];
            out[(size_t)row * 128 + c] = v1 > 0.f ? v1 : 0.01f * v1;
            X2T[(size_t)c * NN + row] = (bf16)(a2[rr] + b2[c]);
        }
    }
}

// ---------------------------------------------------------------------------
// Fused: S = Hx_i @ Hx_j^T (MFMA), gate w = mask? exp(sigmoid(S)) : 0 with
// diag=exp(1), accumulate denom and w @ X2 (MFMA via per-chunk P round-trip).
//
// R2 restructure: ALL matrix fragments (afrag, bfrag, x2 frags) load directly
// global->VGPR with perfectly-coalesced 1KB/instr patterns (the old LDS
// staging had zero cross-wave sharing -- wave w only ever read the rows it
// staged itself). Only the P C-layout->A-layout transform round-trips through
// LDS (4.6 KB). 2 barriers/chunk. Grid 1024 (i-tile 32 x j-split 4);
// js = blockIdx&3 is constant per XCD (round-robin mod 8) -> each XCD's L2
// holds one 1MB Hx j-slab.
#define LDP 72    // P LDS row stride (64 + 8 pad; 2-way-max bank aliasing)

__global__ __launch_bounds__(256, 3) void k_fused(
    const float* __restrict__ A, const bf16* __restrict__ Hx,
    const bf16* __restrict__ X2T, float* __restrict__ pacc,
    float* __restrict__ pden)
{
    __shared__ __align__(16) bf16 P[32 * LDP];

    int t = threadIdx.x;
    int w = t >> 6, l = t & 63;
    int q = l >> 4, li = l & 15;
    int ib = blockIdx.x >> 2, js = blockIdx.x & 3;
    int i0 = ib * 32;
    int jbase = js * 2048;

    // A-fragments for the 32 i-rows, K=256: direct global->reg, coalesced
    bf16x8 afrag[2][8];
#pragma unroll
    for (int mb = 0; mb < 2; ++mb)
#pragma unroll
        for (int k = 0; k < 8; ++k)
            afrag[mb][k] = *(const bf16x8*)&Hx[(size_t)(i0 + mb * 16 + li) * DTH + k * 32 + q * 8];

    f32x4 agg[2] = {{0,0,0,0},{0,0,0,0}};
    float dpart[8] = {0,0,0,0,0,0,0,0};
    int mb_a = w >> 1, cb0 = (w & 1) * 2;

    for (int ch = 0; ch < 32; ++ch) {
        int j0 = jbase + ch * 64;
        int jc = j0 + w * 16 + li;
        // A mask values for this wave's 16 j-columns (issued early)
        float av[8];
#pragma unroll
        for (int mb = 0; mb < 2; ++mb)
#pragma unroll
            for (int r = 0; r < 4; ++r)
                av[mb * 4 + r] = A[(size_t)(i0 + mb * 16 + q * 4 + r) * NN + jc];
        // B-fragments: wave w's 16 j-rows, direct global->reg (16 rows x 64B)
        bf16x8 bfrag[8];
#pragma unroll
        for (int k = 0; k < 8; ++k)
            bfrag[k] = *(const bf16x8*)&Hx[(size_t)(jc) * DTH + k * 32 + q * 8];

        // S tiles: wave w covers j-cols w*16.., both m-tiles, K=256
        f32x4 s0 = {0,0,0,0}, s1 = {0,0,0,0};
#pragma unroll
        for (int k = 0; k < 8; ++k) {
            s0 = __builtin_amdgcn_mfma_f32_16x16x32_bf16(afrag[0][k], bfrag[k], s0, 0, 0, 0);
            s1 = __builtin_amdgcn_mfma_f32_16x16x32_bf16(afrag[1][k], bfrag[k], s1, 0, 0, 0);
        }

        // X2 B-fragments for the agg matmul (in flight during gating)
        bf16x8 xb[2][2];
#pragma unroll
        for (int cbi = 0; cbi < 2; ++cbi)
#pragma unroll
            for (int ks = 0; ks < 2; ++ks)
                xb[cbi][ks] = *(const bf16x8*)&X2T[(size_t)((cb0 + cbi) * 16 + li) * NN + j0 + ks * 32 + q * 8];

        // gate + exp, accumulate denom, write P (C-layout -> row-major LDS)
#pragma unroll
        for (int mb = 0; mb < 2; ++mb) {
            f32x4 sv = mb ? s1 : s0;
#pragma unroll
            for (int r = 0; r < 4; ++r) {
                int ig = i0 + mb * 16 + q * 4 + r;
                float s = sv[r];
                float sig = __builtin_amdgcn_rcpf(1.f + __expf(-s));
                float wv = (av[mb * 4 + r] > 0.f) ? __expf(sig) : 0.f;
                if (ig == jc) wv = 2.71828182845904523f;   // exp(1.0) diag
                dpart[mb * 4 + r] += wv;
                P[(mb * 16 + q * 4 + r) * LDP + w * 16 + li] = (bf16)wv;
            }
        }
        __syncthreads();   // P visible to all waves

        // agg += P @ X2chunk : wave w -> rows mb_a*16.., X2 col tiles cb0..cb0+1
#pragma unroll
        for (int ks = 0; ks < 2; ++ks) {
            bf16x8 pa = *(const bf16x8*)&P[(mb_a * 16 + li) * LDP + ks * 32 + q * 8];
#pragma unroll
            for (int cbi = 0; cbi < 2; ++cbi)
                agg[cbi] = __builtin_amdgcn_mfma_f32_16x16x32_bf16(pa, xb[cbi][ks], agg[cbi], 0, 0, 0);
        }
        __syncthreads();   // all P reads done before next chunk's writes
    }

    // write partial aggregation (each output element owned by 1 wave/block)
#pragma unroll
    for (int cbi = 0; cbi < 2; ++cbi)
#pragma unroll
        for (int r = 0; r < 4; ++r)
            atomicAdd(&pacc[(size_t)(i0 + mb_a * 16 + q * 4 + r) * DH + (cb0 + cbi) * 16 + li],
                      agg[cbi][r]);
    // reduce denom partials across the 16 lanes of each quad-group
#pragma unroll
    for (int idx = 0; idx < 8; ++idx) {
        float v = dpart[idx];
        v += __shfl_xor(v, 1, 64);
        v += __shfl_xor(v, 2, 64);
        v += __shfl_xor(v, 4, 64);
        v += __shfl_xor(v, 8, 64);
        if (li == 0)
            atomicAdd(&pden[i0 + (idx >> 2) * 16 + q * 4 + (idx & 3)], v);
    }
}

// ---------------------------------------------------------------------------
__global__ __launch_bounds__(256) void k_finalize(const float* __restrict__ pacc,
                                                  const float* __restrict__ pden,
                                                  float* __restrict__ out)
{
    int e = blockIdx.x * 256 + threadIdx.x;
    int i = e >> 6, c = e & 63;
    float v = pacc[e] / pden[i];
    out[(size_t)i * 128 + 64 + c] = v > 0.f ? v : 0.01f * v;
}

// ---------------------------------------------------------------------------
extern "C" void kernel_launch(void* const* d_in, const int* in_sizes, int n_in,
                              void* d_out, int out_size, void* d_ws, size_t ws_size,
                              hipStream_t stream)
{
    const float* H     = (const float*)d_in[0];
    const float* A     = (const float*)d_in[1];
    const float* gamma = (const float*)d_in[2];
    const float* beta  = (const float*)d_in[3];
    const float* Wt    = (const float*)d_in[4];
    const float* bt    = (const float*)d_in[5];
    const float* W1    = (const float*)d_in[6];
    const float* b1    = (const float*)d_in[7];
    const float* W2    = (const float*)d_in[8];
    const float* b2    = (const float*)d_in[9];
    float* out = (float*)d_out;

    char* ws = (char*)d_ws;
    float* pacc = (float*)(ws + OFF_PACC);
    float* pden = (float*)(ws + OFF_PDEN);
    float* bns  = (float*)(ws + OFF_BN);
    bf16*  Hx   = (bf16*)(ws + OFF_HX);
    bf16*  X2T  = (bf16*)(ws + OFF_X2T);

    hipMemsetAsync(ws, 0, ZERO_BYTES, stream);
    k_bn_stats<<<256, 256, 0, stream>>>(H, bns);
    k_project<<<512, 256, 0, stream>>>(H, bns, gamma, beta, Wt, bt, W1, b1, W2, b2,
                                       Hx, X2T, out);
    k_fused<<<1024, 256, 0, stream>>>(A, Hx, X2T, pacc, pden);
    k_finalize<<<2048, 256, 0, stream>>>(pacc, pden, out);
}

// Round 3
// 489.552 us; speedup vs baseline: 1.1358x; 1.1358x over previous
//
#include <hip/hip_runtime.h>
#include <hip/hip_bf16.h>

typedef __bf16 bf16;
typedef __bf16 bf16x8 __attribute__((ext_vector_type(8)));
typedef __bf16 bf16x4 __attribute__((ext_vector_type(4)));
typedef float f32x4 __attribute__((ext_vector_type(4)));

// problem sizes
#define NN 8192
#define DIN 128
#define DTH 256
#define DH 64

// workspace layout (bytes)
#define OFF_PACCS 0                          // [4 js][8192][64] f32 partial agg
#define OFF_PDENS (4*8192*64*4)              // [4 js][8192] f32 partial denom
#define OFF_BN    (OFF_PDENS + 4*8192*4)     // 256 f32 bn sums (needs zero)
#define OFF_HX    (OFF_BN + 1024)            // [8192][256] bf16 Hx
#define OFF_X2T   (OFF_HX + 8192*256*2)      // [64][8192] bf16 X2 transposed
#define OFF_WCT   (OFF_X2T + 64*8192*2)      // [384][128] bf16 W concat^T

// ---------------------------------------------------------------------------
// BN statistics (atomic per-feature sum/sumsq) + cast W -> WcatT bf16.
// WcatT[c][k]: c 0..255 = Wt cols, 256..319 = W1 cols, 320..383 = W2 cols.
__global__ __launch_bounds__(256) void k_bn_stats(
    const float* __restrict__ H, float* __restrict__ bns,
    const float* __restrict__ Wt, const float* __restrict__ W1,
    const float* __restrict__ W2, bf16* __restrict__ WcatT)
{
    __shared__ float s1[256], s2[256];
    int t = threadIdx.x;
    int f = t & 127, rh = t >> 7;
    int r0 = blockIdx.x * 32 + rh * 16;
    float a = 0.f, b = 0.f;
#pragma unroll
    for (int rr = 0; rr < 16; ++rr) {
        float x = H[(size_t)(r0 + rr) * DIN + f];
        a += x; b += x * x;
    }
    s1[t] = a; s2[t] = b;
    __syncthreads();
    if (t < 128) {
        atomicAdd(&bns[f], s1[t] + s1[t + 128]);
        atomicAdd(&bns[128 + f], s2[t] + s2[t + 128]);
    }
    // W cast+transpose (gid < 49152)
    int gid = blockIdx.x * 256 + t;
    if (gid < 32768) {                       // Wt [128][256]
        int k = gid >> 8, c = gid & 255;
        WcatT[c * 128 + k] = (bf16)Wt[gid];
    } else if (gid < 40960) {                // W1 [128][64]
        int g = gid - 32768, k = g >> 6, c = g & 63;
        WcatT[(256 + c) * 128 + k] = (bf16)W1[g];
    } else if (gid < 49152) {                // W2 [128][64]
        int g = gid - 40960, k = g >> 6, c = g & 63;
        WcatT[(320 + c) * 128 + k] = (bf16)W2[g];
    }
}

// ---------------------------------------------------------------------------
// MFMA projection: block = 32 rows. Hn (BN-applied, bf16) @ WcatT^T -> 384
// cols: [0,256)->Hx, [256,320)->out1 (leaky, fp32 out), [320,384)->X2T
// (transposed through LDS for coalesced writes).
#define LDH2 136   // hn row stride (128+8)
#define LDX2 40    // x2s row stride (32+8; 80B keeps b128 16B-aligned)

__global__ __launch_bounds__(256) void k_project(
    const float* __restrict__ H, const float* __restrict__ bns,
    const float* __restrict__ gamma, const float* __restrict__ beta,
    const bf16* __restrict__ WcatT, const float* __restrict__ bt,
    const float* __restrict__ b1, const float* __restrict__ b2,
    bf16* __restrict__ Hx, bf16* __restrict__ X2T, float* __restrict__ out)
{
    __shared__ __align__(16) bf16 hn[32 * LDH2];
    __shared__ __align__(16) bf16 x2s[64 * LDX2];
    int t = threadIdx.x;
    int w = t >> 6, l = t & 63, q = l >> 4, li = l & 15;
    int i0 = blockIdx.x * 32;
    {   // BN apply: thread owns 4 fixed cols, 8 rows (float4 loads)
        int c4 = (t & 31) * 4;
        float mean[4], sc[4], sh[4];
#pragma unroll
        for (int j = 0; j < 4; ++j) {
            int c = c4 + j;
            float m = bns[c] * (1.f / 8192.f);
            float v = bns[128 + c] * (1.f / 8192.f) - m * m;
            mean[j] = m; sc[j] = rsqrtf(v + 1e-5f) * gamma[c]; sh[j] = beta[c];
        }
#pragma unroll
        for (int p = 0; p < 4; ++p) {
            int row = (t >> 5) + 8 * p;
            float4 x = *(const float4*)&H[(size_t)(i0 + row) * DIN + c4];
            bf16x4 o;
            o[0] = (bf16)((x.x - mean[0]) * sc[0] + sh[0]);
            o[1] = (bf16)((x.y - mean[1]) * sc[1] + sh[1]);
            o[2] = (bf16)((x.z - mean[2]) * sc[2] + sh[2]);
            o[3] = (bf16)((x.w - mean[3]) * sc[3] + sh[3]);
            *(bf16x4*)&hn[row * LDH2 + c4] = o;
        }
    }
    __syncthreads();
    // GEMM: [32 x 128] @ [128 x 384]; wave w owns n-cols [w*96, w*96+96)
    f32x4 acc[2][6] = {};
#pragma unroll
    for (int k = 0; k < 4; ++k) {
        bf16x8 af0 = *(const bf16x8*)&hn[li * LDH2 + k * 32 + q * 8];
        bf16x8 af1 = *(const bf16x8*)&hn[(16 + li) * LDH2 + k * 32 + q * 8];
#pragma unroll
        for (int j = 0; j < 6; ++j) {
            int c = w * 96 + j * 16 + li;
            bf16x8 bf_ = *(const bf16x8*)&WcatT[(size_t)c * 128 + k * 32 + q * 8];
            acc[0][j] = __builtin_amdgcn_mfma_f32_16x16x32_bf16(af0, bf_, acc[0][j], 0, 0, 0);
            acc[1][j] = __builtin_amdgcn_mfma_f32_16x16x32_bf16(af1, bf_, acc[1][j], 0, 0, 0);
        }
    }
    // epilogue (branch is uniform per (w,j))
#pragma unroll
    for (int j = 0; j < 6; ++j) {
        int c0 = w * 96 + j * 16 + li;
        if (c0 < 256) {
            float bb = bt[c0];
#pragma unroll
            for (int mt = 0; mt < 2; ++mt)
#pragma unroll
                for (int rr = 0; rr < 4; ++rr) {
                    int row = i0 + mt * 16 + q * 4 + rr;
                    Hx[(size_t)row * DTH + c0] = (bf16)(acc[mt][j][rr] + bb);
                }
        } else if (c0 < 320) {
            float bb = b1[c0 - 256];
#pragma unroll
            for (int mt = 0; mt < 2; ++mt)
#pragma unroll
                for (int rr = 0; rr < 4; ++rr) {
                    int row = i0 + mt * 16 + q * 4 + rr;
                    float v = acc[mt][j][rr] + bb;
                    out[(size_t)row * 128 + (c0 - 256)] = v > 0.f ? v : 0.01f * v;
                }
        } else {
            float bb = b2[c0 - 320];
#pragma unroll
            for (int mt = 0; mt < 2; ++mt)
#pragma unroll
                for (int rr = 0; rr < 4; ++rr)
                    x2s[(c0 - 320) * LDX2 + mt * 16 + q * 4 + rr] =
                        (bf16)(acc[mt][j][rr] + bb);
        }
    }
    __syncthreads();
    {   // X2T coalesced writeout: thread -> (col c, 8-row segment)
        int c = t >> 2, sg = t & 3;
        bf16x8 v = *(const bf16x8*)&x2s[c * LDX2 + sg * 8];
        *(bf16x8*)&X2T[(size_t)c * NN + i0 + sg * 8] = v;
    }
}

// ---------------------------------------------------------------------------
// Fused gate+aggregate. i-tile 64 (afrag persistent in regs), j-split 4,
// chunks of 64 j. LDS staging (2-txn coalesced) for hxj + double-buffered
// x2t; P round-trip for the C->A layout transform. 2 barriers/chunk.
// Denominator = P @ ones via a constant B-fragment. Per-js output slices
// (no atomics, no zero-init).
#define LDH 264   // hxj row stride (256+8)
#define LDP 72    // P / x2t row stride (64+8)

__global__ __launch_bounds__(256, 2) void k_fused(
    const float* __restrict__ A, const bf16* __restrict__ Hx,
    const bf16* __restrict__ X2T, float* __restrict__ paccS,
    float* __restrict__ pdenS)
{
    __shared__ __align__(16) bf16 hxj[64 * LDH];
    __shared__ __align__(16) bf16 x2t[2][64 * LDP];
    __shared__ __align__(16) bf16 P[64 * LDP];

    int t = threadIdx.x;
    int w = t >> 6, l = t & 63, q = l >> 4, li = l & 15;
    int ib = blockIdx.x >> 2, js = blockIdx.x & 3;
    int i0 = ib * 64, jbase = js * 2048;

    // persistent A-fragments: 64 i-rows, K=256 (one-time gather)
    bf16x8 afrag[4][8];
#pragma unroll
    for (int mt = 0; mt < 4; ++mt)
#pragma unroll
        for (int k = 0; k < 8; ++k)
            afrag[mt][k] = *(const bf16x8*)&Hx[(size_t)(i0 + mt * 16 + li) * DTH + k * 32 + q * 8];

    f32x4 agg[4] = {};
    f32x4 agg4 = {};
    bf16 onev = (bf16)1.0f;
    bf16x8 ones = {onev, onev, onev, onev, onev, onev, onev, onev};

    for (int ch = 0; ch < 32; ++ch) {
        int j0 = jbase + ch * 64;
        int jc = j0 + w * 16 + li;
        int buf = ch & 1;
        // stage Hx_j (64 x 512B) -- 2 txns per instr
#pragma unroll
        for (int p = 0; p < 8; ++p) {
            int u = t + p * 256, row = u >> 5, seg = u & 31;
            *(bf16x8*)&hxj[row * LDH + seg * 8] =
                *(const bf16x8*)&Hx[(size_t)(j0 + row) * DTH + seg * 8];
        }
        // stage x2t chunk (64 cols x 64 j), double-buffered
#pragma unroll
        for (int p = 0; p < 2; ++p) {
            int u = t + p * 256, c = u >> 3, sg = u & 7;
            *(bf16x8*)&x2t[buf][c * LDP + sg * 8] =
                *(const bf16x8*)&X2T[(size_t)c * NN + j0 + sg * 8];
        }
        // adjacency mask values (in flight across the barrier region)
        float av[16];
#pragma unroll
        for (int mt = 0; mt < 4; ++mt)
#pragma unroll
            for (int r = 0; r < 4; ++r)
                av[mt * 4 + r] = A[(size_t)(i0 + mt * 16 + q * 4 + r) * NN + jc];
        __syncthreads();   // staging visible

        // S = Hx_i @ Hx_j^T : wave w -> j-cols [w*16, w*16+16), all 4 m-tiles
        f32x4 s[4] = {};
#pragma unroll
        for (int k = 0; k < 8; ++k) {
            bf16x8 bfr = *(const bf16x8*)&hxj[(w * 16 + li) * LDH + k * 32 + q * 8];
#pragma unroll
            for (int mt = 0; mt < 4; ++mt)
                s[mt] = __builtin_amdgcn_mfma_f32_16x16x32_bf16(afrag[mt][k], bfr, s[mt], 0, 0, 0);
        }
        // gate: w = mask ? exp(sigmoid(S)) : 0, diag = e; write P
#pragma unroll
        for (int mt = 0; mt < 4; ++mt)
#pragma unroll
            for (int r = 0; r < 4; ++r) {
                int ig = i0 + mt * 16 + q * 4 + r;
                float sv = s[mt][r];
                float sig = __builtin_amdgcn_rcpf(1.f + __expf(-sv));
                float wv = (av[mt * 4 + r] > 0.f) ? __expf(sig) : 0.f;
                if (ig == jc) wv = 2.71828182845904523f;
                P[(mt * 16 + q * 4 + r) * LDP + w * 16 + li] = (bf16)wv;
            }
        __syncthreads();   // P visible

        // agg += P @ X2chunk : wave w -> out rows [w*16, w*16+16), all 4 col
        // tiles + ones-column (denominator)
#pragma unroll
        for (int ks = 0; ks < 2; ++ks) {
            bf16x8 pa = *(const bf16x8*)&P[(w * 16 + li) * LDP + ks * 32 + q * 8];
#pragma unroll
            for (int cb = 0; cb < 4; ++cb) {
                bf16x8 xb = *(const bf16x8*)&x2t[buf][(cb * 16 + li) * LDP + ks * 32 + q * 8];
                agg[cb] = __builtin_amdgcn_mfma_f32_16x16x32_bf16(pa, xb, agg[cb], 0, 0, 0);
            }
            agg4 = __builtin_amdgcn_mfma_f32_16x16x32_bf16(pa, ones, agg4, 0, 0, 0);
        }
        // no 3rd barrier needed: hxj reads done before barrier B; next P
        // writes happen after next barrier A; x2t is double-buffered.
    }

    // per-js slice writeout (each element written exactly once)
#pragma unroll
    for (int cb = 0; cb < 4; ++cb)
#pragma unroll
        for (int r = 0; r < 4; ++r)
            paccS[(size_t)js * (8192 * 64) + (size_t)(i0 + w * 16 + q * 4 + r) * DH + cb * 16 + li] =
                agg[cb][r];
    if (li == 0) {
#pragma unroll
        for (int r = 0; r < 4; ++r)
            pdenS[js * 8192 + i0 + w * 16 + q * 4 + r] = agg4[r];
    }
}

// ---------------------------------------------------------------------------
__global__ __launch_bounds__(256) void k_finalize(const float* __restrict__ paccS,
                                                  const float* __restrict__ pdenS,
                                                  float* __restrict__ out)
{
    int e = blockIdx.x * 256 + threadIdx.x;
    int i = e >> 6, c = e & 63;
    float num = 0.f, den = 0.f;
#pragma unroll
    for (int js = 0; js < 4; ++js) {
        num += paccS[(size_t)js * (8192 * 64) + e];
        den += pdenS[js * 8192 + i];
    }
    float v = num / den;
    out[(size_t)i * 128 + 64 + c] = v > 0.f ? v : 0.01f * v;
}

// ---------------------------------------------------------------------------
extern "C" void kernel_launch(void* const* d_in, const int* in_sizes, int n_in,
                              void* d_out, int out_size, void* d_ws, size_t ws_size,
                              hipStream_t stream)
{
    const float* H     = (const float*)d_in[0];
    const float* A     = (const float*)d_in[1];
    const float* gamma = (const float*)d_in[2];
    const float* beta  = (const float*)d_in[3];
    const float* Wt    = (const float*)d_in[4];
    const float* bt    = (const float*)d_in[5];
    const float* W1    = (const float*)d_in[6];
    const float* b1    = (const float*)d_in[7];
    const float* W2    = (const float*)d_in[8];
    const float* b2    = (const float*)d_in[9];
    float* out = (float*)d_out;

    char* ws = (char*)d_ws;
    float* paccS = (float*)(ws + OFF_PACCS);
    float* pdenS = (float*)(ws + OFF_PDENS);
    float* bns   = (float*)(ws + OFF_BN);
    bf16*  Hx    = (bf16*)(ws + OFF_HX);
    bf16*  X2T   = (bf16*)(ws + OFF_X2T);
    bf16*  WcatT = (bf16*)(ws + OFF_WCT);

    hipMemsetAsync(bns, 0, 1024, stream);
    k_bn_stats<<<256, 256, 0, stream>>>(H, bns, Wt, W1, W2, WcatT);
    k_project<<<256, 256, 0, stream>>>(H, bns, gamma, beta, WcatT, bt, b1, b2,
                                       Hx, X2T, out);
    k_fused<<<512, 256, 0, stream>>>(A, Hx, X2T, paccS, pdenS);
    k_finalize<<<2048, 256, 0, stream>>>(paccS, pdenS, out);
}